// Round 2
// baseline (283.409 us; speedup 1.0000x reference)
//
#include <hip/hip_runtime.h>
#include <cstddef>

namespace {

constexpr int IMG   = 256;
constexpr int TILE  = 64;
constexpr int BSTR  = 100;           // LDS row stride (floats); 100%32=4 -> banks rotate per row
constexpr int BROWS = 98;            // rows 0..97 touched (reads up to start+6 = 97)
constexpr int BUFSZ = BROWS * BSTR;  // 9800 floats
constexpr int NTHR  = 384;
constexpr int NCG   = 24;            // 24 column groups * 4 cols = 96
constexpr int STRIP = 6;             // rows per thread
constexpr int STEPS = 15;
constexpr long long N_ELEM = 16LL * 8 * IMG * IMG;   // 8388608

constexpr float RP   = 3.9f;
constexpr float EPSF = 0.3f;
constexpr float OME  = 0.7f;    // 1 - EPS
constexpr float BET  = 0.15f;
constexpr float OMB  = 0.85f;   // 1 - BETA
constexpr float CLO  = 1e-4f;
constexpr float CHI  = (float)(1.0 - 1e-4);

__device__ __forceinline__ float mapf(float g) {
#pragma clang fp contract(off)
    float t = RP * g;          // match numpy op order: (R*g) * (1-g)
    float m = t * (1.0f - g);
    return m;
}

// guarded float4 load; x is always 0 mod 4 and image edges are 0 mod 4,
// so validity is all-or-nothing per float4.
__device__ __forceinline__ float4 load4g(const float* __restrict__ im, int y, int x) {
    bool v = ((unsigned)y < (unsigned)IMG) && ((unsigned)x < (unsigned)IMG);
    const float* p = im + (v ? (y * IMG + x) : 0);
    float4 r = *(const float4*)p;
    if (!v) { r.x = 0.f; r.y = 0.f; r.z = 0.f; r.w = 0.f; }
    return r;
}

// read MAPPED row r: own quad via ds_read_b128, halos via lane shuffles.
// Shuffle partners that cross a cg-group boundary deliver wrong-row data,
// but exactly for lanes whose halo is in the dead validity margin.
// Wave-boundary lanes with a live halo (fixL/fixR) take a 1-lane LDS read.
__device__ __forceinline__ void loadrow(const float* __restrict__ buf, int r, int c4,
                                        bool fixL, bool fixR, float w[6]) {
    const float* p = buf + r * BSTR + c4;
    float4 m = *(const float4*)p;   // ds_read_b128
    w[1] = m.x; w[2] = m.y; w[3] = m.z; w[4] = m.w;
    w[0] = __shfl_up(m.w, 1);       // lane-1's col c4-1
    w[5] = __shfl_down(m.x, 1);     // lane+1's col c4+4
    if (fixL) w[0] = p[-1];
    if (fixR) w[5] = p[4];
}

__device__ __forceinline__ float conv3(const float k[9], const float A[6], const float B[6],
                                       const float C[6], int j) {
    float a = k[0] * A[j];
    a = fmaf(k[1], A[j + 1], a);
    a = fmaf(k[2], A[j + 2], a);
    a = fmaf(k[3], B[j],     a);
    a = fmaf(k[4], B[j + 1], a);
    a = fmaf(k[5], B[j + 2], a);
    a = fmaf(k[6], C[j],     a);
    a = fmaf(k[7], C[j + 1], a);
    a = fmaf(k[8], C[j + 2], a);
    return a;
}

// one output row: A = mapped row r-1, B = row r, C = row r+1 (loaded here)
// F: final step -> store raw g (for epilogue); else store mapf(g)
#define ROW_BODY(i, A, B, C, F) {                                                \
    const int r_ = start + (i);                                                  \
    loadrow(src, r_ + 1, c4, fixL, fixR, C);                                     \
    float go_[4];                                                                \
    _Pragma("unroll")                                                            \
    for (int j = 0; j < 4; ++j) {                                                \
        float a_  = conv3(k, A, B, C, j);                                        \
        float ph_ = fmaf(EPSF, a_, OME * B[j + 1]);                              \
        float g_  = fmaf(BET, dv[(i) * 4 + j], OMB * ph_);                       \
        g_ = fminf(fmaxf(g_, CLO), CHI);                                         \
        if (EDGE) g_ = rowok[i] ? g_ : 0.0f;                                     \
        sum[(i) * 4 + j] += g_;                                                  \
        sq[(i) * 4 + j]  = fmaf(g_, g_, sq[(i) * 4 + j]);                        \
        if (F) go_[j] = g_; else go_[j] = mapf(g_);                              \
    }                                                                            \
    float4 o_; o_.x = go_[0]; o_.y = go_[1]; o_.z = go_[2]; o_.w = go_[3];       \
    *(float4*)(dst + r_ * BSTR + c4) = o_;                                       \
}

#define STEP_BODY(F) {                                                           \
    float w0[6], w1[6], w2[6];                                                   \
    loadrow(src, start - 1, c4, fixL, fixR, w0);                                 \
    loadrow(src, start,     c4, fixL, fixR, w1);                                 \
    ROW_BODY(0, w0, w1, w2, F)                                                   \
    ROW_BODY(1, w1, w2, w0, F)                                                   \
    ROW_BODY(2, w2, w0, w1, F)                                                   \
    ROW_BODY(3, w0, w1, w2, F)                                                   \
    ROW_BODY(4, w1, w2, w0, F)                                                   \
    ROW_BODY(5, w2, w0, w1, F)                                                   \
}

template<bool EDGE>
__device__ __forceinline__ void run_tile(const float* __restrict__ drive,
                                         const float* __restrict__ Kl,
                                         float* __restrict__ out,
                                         int img, int ty, int tx, float* lds0)
{
    const int tid = threadIdx.x;
    const int cg  = (int)((unsigned)tid % (unsigned)NCG);
    const int rt  = (int)((unsigned)tid / (unsigned)NCG);
    const int c4  = cg * 4;
    const int start = 1 + rt * STRIP;
    const int lane = tid & 63;
    const bool fixL = (lane == 0)  && (cg != 0);
    const bool fixR = (lane == 63) && (cg != 23);

    const int ch = img & 7;
    float k[9];
#pragma unroll
    for (int i = 0; i < 9; ++i) k[i] = Kl[ch * 9 + i];

    const float* dimg = drive + (size_t)img * (IMG * IMG);
    const int y0 = ty * TILE - 16;   // image y of buffer row 0
    const int x0 = tx * TILE - 16;   // image x of buffer col 0
    const int xg = x0 + c4;
    const bool xok = ((unsigned)xg < (unsigned)IMG);

    float* buf0 = lds0;
    float* buf1 = lds0 + BUFSZ;

    // ---- load g0 = drive, store MAPPED values into buf0 (mapf(0)=0 keeps zero-pad)
#pragma unroll
    for (int it = 0; it < 6; ++it) {
        int task = tid + it * NTHR;
        if (task < 95 * 24) {
            int r = (int)((unsigned)task / 24u);
            int c = (int)((unsigned)task % 24u) * 4;
            int y = y0 + r, x = x0 + c;
            float4 v;
            if (EDGE) v = load4g(dimg, y, x);
            else      v = *(const float4*)(dimg + y * IMG + x);
            float4 m; m.x = mapf(v.x); m.y = mapf(v.y); m.z = mapf(v.z); m.w = mapf(v.w);
            *(float4*)(buf0 + r * BSTR + c) = m;
        }
    }

    // ---- own drive pixels -> registers (reused all 15 steps + epilogue)
    float dv[STRIP * 4];
    bool rowok[STRIP];
#pragma unroll
    for (int i = 0; i < STRIP; ++i) {
        const int y = y0 + start + i;
        rowok[i] = xok && ((unsigned)y < (unsigned)IMG);
        float4 t;
        if (EDGE) t = load4g(dimg, y, xg);
        else      t = *(const float4*)(dimg + y * IMG + xg);
        dv[i * 4 + 0] = t.x; dv[i * 4 + 1] = t.y;
        dv[i * 4 + 2] = t.z; dv[i * 4 + 3] = t.w;
    }

    float sum[STRIP * 4], sq[STRIP * 4];
#pragma unroll
    for (int i = 0; i < STRIP * 4; ++i) { sum[i] = 0.f; sq[i] = 0.f; }

    __syncthreads();

    for (int s = 0; s < STEPS - 1; ++s) {
        const float* src = (s & 1) ? buf1 : buf0;
        float*       dst = (s & 1) ? buf0 : buf1;
        STEP_BODY(0)
        __syncthreads();
    }
    {   // final step (s = 14, even): src buf0, dst buf1; store raw g
        const float* src = buf0;
        float*       dst = buf1;
        STEP_BODY(1)
        __syncthreads();
    }

    // ---- epilogue: each thread owns its strip's inner pixels
    const float* fin = buf1;
    const bool colin = (c4 >= 16) && (c4 <= 76);
    const float inv15 = 1.0f / 15.0f;

#pragma unroll
    for (int i = 0; i < STRIP; ++i) {
        const int r = start + i;
        const bool rowin = (r >= 16) && (r <= 79);
        if (colin && rowin) {
            float4 g4 = *(const float4*)(fin + r * BSTR + c4);
            const int y = y0 + r;
            const int x = xg;
            float gg[4] = {g4.x, g4.y, g4.z, g4.w};
            float mn[4], vr[4], dl[4];
#pragma unroll
            for (int j = 0; j < 4; ++j) {
                float m = sum[i * 4 + j] * inv15;
                float v = fmaf(-m, m, sq[i * 4 + j] * inv15);
                vr[j] = fmaxf(v, 0.0f);
                mn[j] = m;
                dl[j] = gg[j] - dv[i * 4 + j];
            }
            size_t base = (size_t)img * (IMG * IMG) + (size_t)y * IMG + x;
            float4 m4; m4.x = mn[0]; m4.y = mn[1]; m4.z = mn[2]; m4.w = mn[3];
            float4 v4; v4.x = vr[0]; v4.y = vr[1]; v4.z = vr[2]; v4.w = vr[3];
            float4 d4; d4.x = dl[0]; d4.y = dl[1]; d4.z = dl[2]; d4.w = dl[3];
            *(float4*)(out + 0 * N_ELEM + base) = g4;   // last
            *(float4*)(out + 1 * N_ELEM + base) = m4;   // mean
            *(float4*)(out + 2 * N_ELEM + base) = v4;   // var
            *(float4*)(out + 3 * N_ELEM + base) = d4;   // delta
            *(float4*)(out + 4 * N_ELEM + base) = d4;   // last_drive
        }
    }
}

__global__ __launch_bounds__(NTHR, 3)
void cml_kernel(const float* __restrict__ drive,
                const float* __restrict__ Kl,
                float* __restrict__ out)
{
    __shared__ __align__(16) float lds[4 + 2 * BUFSZ + 8];
    const int bx  = blockIdx.x;
    const int img = bx >> 4;         // 0..127  (b*8 + c)
    const int t   = bx & 15;
    const int ty  = t >> 2, tx = t & 3;
    const bool edge = (ty == 0) | (ty == 3) | (tx == 0) | (tx == 3);
    if (edge) run_tile<true >(drive, Kl, out, img, ty, tx, lds + 4);
    else      run_tile<false>(drive, Kl, out, img, ty, tx, lds + 4);
}

} // namespace

extern "C" void kernel_launch(void* const* d_in, const int* in_sizes, int n_in,
                              void* d_out, int out_size, void* d_ws, size_t ws_size,
                              hipStream_t stream) {
    const float* drive = (const float*)d_in[0];
    const float* Kl    = (const float*)d_in[1];
    float* out         = (float*)d_out;
    (void)in_sizes; (void)n_in; (void)out_size; (void)d_ws; (void)ws_size;

    dim3 grid(128 * 16);   // 128 images * 16 tiles (64x64)
    dim3 block(NTHR);
    cml_kernel<<<grid, block, 0, stream>>>(drive, Kl, out);
}

// Round 3
// 258.982 us; speedup vs baseline: 1.0943x; 1.0943x over previous
//
#include <hip/hip_runtime.h>
#include <cstddef>

namespace {

constexpr int IMG   = 256;
constexpr int TILE  = 64;
constexpr int BSTR  = 100;           // LDS row stride (floats); 100%32=4 -> banks rotate per row
constexpr int BROWS = 98;            // rows 0..97 touched (reads up to start+6 = 97)
constexpr int BUFSZ = BROWS * BSTR;  // 9800 floats (39.2 KB) -- SINGLE buffer now
constexpr int NTHR  = 384;
constexpr int NCG   = 24;            // 24 column groups * 4 cols = 96
constexpr int STRIP = 6;             // rows per thread
constexpr int STEPS = 15;
constexpr long long N_ELEM = 16LL * 8 * IMG * IMG;   // 8388608

constexpr float RP   = 3.9f;
constexpr float EPSF = 0.3f;
constexpr float OME  = 0.7f;    // 1 - EPS
constexpr float BET  = 0.15f;
constexpr float OMB  = 0.85f;   // 1 - BETA
constexpr float CLO  = 1e-4f;
constexpr float CHI  = (float)(1.0 - 1e-4);

__device__ __forceinline__ float mapf(float g) {
#pragma clang fp contract(off)
    float t = RP * g;          // match numpy op order: (R*g) * (1-g)
    float m = t * (1.0f - g);
    return m;
}

// guarded float4 load; x is always 0 mod 4 and image edges are 0 mod 4,
// so validity is all-or-nothing per float4.
__device__ __forceinline__ float4 load4g(const float* __restrict__ im, int y, int x) {
    bool v = ((unsigned)y < (unsigned)IMG) && ((unsigned)x < (unsigned)IMG);
    const float* p = im + (v ? (y * IMG + x) : 0);
    float4 r = *(const float4*)p;
    if (!v) { r.x = 0.f; r.y = 0.f; r.z = 0.f; r.w = 0.f; }
    return r;
}

// read MAPPED row r: own quad via ds_read_b128, halos via lane shuffles.
// Shuffle partners that cross a cg-group boundary deliver wrong-row data,
// but exactly for lanes whose halo is in the dead validity margin.
// Wave-boundary lanes with a live halo (fixL/fixR) take a 1-lane LDS read.
__device__ __forceinline__ void loadrow(const float* __restrict__ buf, int r, int c4,
                                        bool fixL, bool fixR, float w[6]) {
    const float* p = buf + r * BSTR + c4;
    float4 m = *(const float4*)p;   // ds_read_b128
    w[1] = m.x; w[2] = m.y; w[3] = m.z; w[4] = m.w;
    w[0] = __shfl_up(m.w, 1);       // lane-1's col c4-1
    w[5] = __shfl_down(m.x, 1);     // lane+1's col c4+4
    if (fixL) w[0] = p[-1];
    if (fixR) w[5] = p[4];
}

__device__ __forceinline__ float conv3(const float k[9], const float A[6], const float B[6],
                                       const float C[6], int j) {
    float a = k[0] * A[j];
    a = fmaf(k[1], A[j + 1], a);
    a = fmaf(k[2], A[j + 2], a);
    a = fmaf(k[3], B[j],     a);
    a = fmaf(k[4], B[j + 1], a);
    a = fmaf(k[5], B[j + 2], a);
    a = fmaf(k[6], C[j],     a);
    a = fmaf(k[7], C[j + 1], a);
    a = fmaf(k[8], C[j + 2], a);
    return a;
}

// one output row: A = mapped row r-1, B = row r, C = row r+1 (loaded here).
// Output is STAGED into registers (stg[i]); LDS write happens after a barrier.
// F: final step -> stage raw g (for epilogue); else stage mapf(g)
#define ROW_BODY(i, A, B, C, F) {                                                \
    const int r_ = start + (i);                                                  \
    loadrow(buf, r_ + 1, c4, fixL, fixR, C);                                     \
    bool ok_ = true;                                                             \
    if (EDGE) ok_ = xok && ((unsigned)(y0 + r_) < (unsigned)IMG);                \
    float go_[4];                                                                \
    _Pragma("unroll")                                                            \
    for (int j = 0; j < 4; ++j) {                                                \
        float a_  = conv3(k, A, B, C, j);                                        \
        float ph_ = fmaf(EPSF, a_, OME * B[j + 1]);                              \
        float g_  = fmaf(BET, dv[(i) * 4 + j], OMB * ph_);                       \
        g_ = fminf(fmaxf(g_, CLO), CHI);                                         \
        if (EDGE) g_ = ok_ ? g_ : 0.0f;                                          \
        sum[(i) * 4 + j] += g_;                                                  \
        sq[(i) * 4 + j]  = fmaf(g_, g_, sq[(i) * 4 + j]);                        \
        if (F) go_[j] = g_; else go_[j] = mapf(g_);                              \
    }                                                                            \
    stg[i].x = go_[0]; stg[i].y = go_[1]; stg[i].z = go_[2]; stg[i].w = go_[3];  \
}

#define STEP_COMPUTE(F) {                                                        \
    float w0[6], w1[6], w2[6];                                                   \
    loadrow(buf, start - 1, c4, fixL, fixR, w0);                                 \
    loadrow(buf, start,     c4, fixL, fixR, w1);                                 \
    ROW_BODY(0, w0, w1, w2, F)                                                   \
    ROW_BODY(1, w1, w2, w0, F)                                                   \
    ROW_BODY(2, w2, w0, w1, F)                                                   \
    ROW_BODY(3, w0, w1, w2, F)                                                   \
    ROW_BODY(4, w1, w2, w0, F)                                                   \
    ROW_BODY(5, w2, w0, w1, F)                                                   \
}

template<bool EDGE>
__device__ __forceinline__ void run_tile(const float* __restrict__ drive,
                                         const float* __restrict__ Kl,
                                         float* __restrict__ out,
                                         int img, int ty, int tx, float* buf)
{
    const int tid = threadIdx.x;
    const int cg  = (int)((unsigned)tid % (unsigned)NCG);
    const int rt  = (int)((unsigned)tid / (unsigned)NCG);
    const int c4  = cg * 4;
    const int start = 1 + rt * STRIP;
    const int lane = tid & 63;
    const bool fixL = (lane == 0)  && (cg != 0);
    const bool fixR = (lane == 63) && (cg != 23);

    const int ch = img & 7;
    float k[9];
#pragma unroll
    for (int i = 0; i < 9; ++i) k[i] = Kl[ch * 9 + i];

    const float* dimg = drive + (size_t)img * (IMG * IMG);
    const int y0 = ty * TILE - 16;   // image y of buffer row 0
    const int x0 = tx * TILE - 16;   // image x of buffer col 0
    const int xg = x0 + c4;
    const bool xok = ((unsigned)xg < (unsigned)IMG);

    // ---- load g0 = drive, store MAPPED values (mapf(0)=0 keeps zero-pad)
#pragma unroll
    for (int it = 0; it < 6; ++it) {
        int task = tid + it * NTHR;
        if (task < 95 * 24) {
            int r = (int)((unsigned)task / 24u);
            int c = (int)((unsigned)task % 24u) * 4;
            int y = y0 + r, x = x0 + c;
            float4 v;
            if (EDGE) v = load4g(dimg, y, x);
            else      v = *(const float4*)(dimg + y * IMG + x);
            float4 m; m.x = mapf(v.x); m.y = mapf(v.y); m.z = mapf(v.z); m.w = mapf(v.w);
            *(float4*)(buf + r * BSTR + c) = m;
        }
    }

    // ---- own drive pixels -> registers (reused all 15 steps + epilogue)
    float dv[STRIP * 4];
#pragma unroll
    for (int i = 0; i < STRIP; ++i) {
        const int y = y0 + start + i;
        float4 t;
        if (EDGE) t = load4g(dimg, y, xg);
        else      t = *(const float4*)(dimg + y * IMG + xg);
        dv[i * 4 + 0] = t.x; dv[i * 4 + 1] = t.y;
        dv[i * 4 + 2] = t.z; dv[i * 4 + 3] = t.w;
    }

    float sum[STRIP * 4], sq[STRIP * 4];
#pragma unroll
    for (int i = 0; i < STRIP * 4; ++i) { sum[i] = 0.f; sq[i] = 0.f; }

    float4 stg[STRIP];

    __syncthreads();

    // steps 0..13: compute into registers, barrier, write in place, barrier
    for (int s = 0; s < STEPS - 1; ++s) {
        STEP_COMPUTE(0)
        __syncthreads();
#pragma unroll
        for (int i = 0; i < STRIP; ++i)
            *(float4*)(buf + (start + i) * BSTR + c4) = stg[i];
        __syncthreads();
    }
    // final step: compute only (raw g stays in stg); epilogue is register-only
    STEP_COMPUTE(1)

    // ---- epilogue: each thread owns its strip's inner pixels (all in regs)
    const bool colin = (c4 >= 16) && (c4 <= 76);
    const float inv15 = 1.0f / 15.0f;

#pragma unroll
    for (int i = 0; i < STRIP; ++i) {
        const int r = start + i;
        const bool rowin = (r >= 16) && (r <= 79);
        if (colin && rowin) {
            const int y = y0 + r;
            const int x = xg;
            float gg[4] = {stg[i].x, stg[i].y, stg[i].z, stg[i].w};
            float mn[4], vr[4], dl[4];
#pragma unroll
            for (int j = 0; j < 4; ++j) {
                float m = sum[i * 4 + j] * inv15;
                float v = fmaf(-m, m, sq[i * 4 + j] * inv15);
                vr[j] = fmaxf(v, 0.0f);
                mn[j] = m;
                dl[j] = gg[j] - dv[i * 4 + j];
            }
            size_t base = (size_t)img * (IMG * IMG) + (size_t)y * IMG + x;
            float4 g4; g4.x = gg[0]; g4.y = gg[1]; g4.z = gg[2]; g4.w = gg[3];
            float4 m4; m4.x = mn[0]; m4.y = mn[1]; m4.z = mn[2]; m4.w = mn[3];
            float4 v4; v4.x = vr[0]; v4.y = vr[1]; v4.z = vr[2]; v4.w = vr[3];
            float4 d4; d4.x = dl[0]; d4.y = dl[1]; d4.z = dl[2]; d4.w = dl[3];
            *(float4*)(out + 0 * N_ELEM + base) = g4;   // last
            *(float4*)(out + 1 * N_ELEM + base) = m4;   // mean
            *(float4*)(out + 2 * N_ELEM + base) = v4;   // var
            *(float4*)(out + 3 * N_ELEM + base) = d4;   // delta
            *(float4*)(out + 4 * N_ELEM + base) = d4;   // last_drive
        }
    }
}

__global__ __launch_bounds__(NTHR, 4)
void cml_kernel(const float* __restrict__ drive,
                const float* __restrict__ Kl,
                float* __restrict__ out)
{
    __shared__ __align__(16) float lds[BUFSZ + 8];
    const int bx  = blockIdx.x;
    const int img = bx >> 4;         // 0..127  (b*8 + c)
    const int t   = bx & 15;
    const int ty  = t >> 2, tx = t & 3;
    const bool edge = (ty == 0) | (ty == 3) | (tx == 0) | (tx == 3);
    if (edge) run_tile<true >(drive, Kl, out, img, ty, tx, lds);
    else      run_tile<false>(drive, Kl, out, img, ty, tx, lds);
}

} // namespace

extern "C" void kernel_launch(void* const* d_in, const int* in_sizes, int n_in,
                              void* d_out, int out_size, void* d_ws, size_t ws_size,
                              hipStream_t stream) {
    const float* drive = (const float*)d_in[0];
    const float* Kl    = (const float*)d_in[1];
    float* out         = (float*)d_out;
    (void)in_sizes; (void)n_in; (void)out_size; (void)d_ws; (void)ws_size;

    dim3 grid(128 * 16);   // 128 images * 16 tiles (64x64)
    dim3 block(NTHR);
    cml_kernel<<<grid, block, 0, stream>>>(drive, Kl, out);
}